// Round 1
// baseline (3336.481 us; speedup 1.0000x reference)
//
#include <hip/hip_runtime.h>
#include <hip/hip_bf16.h>

// ---------------- problem constants ----------------
#define BB 16
#define SS 100
#define HH 400      // hidden per direction
#define H2 800
#define G4 1600     // 4*H gate rows
#define DIN0 150    // WE+PE

// ---------------- workspace layout (float offsets) ----------------
#define OFF_X0   0ULL          // 240,000
#define OFF_GF   240000ULL     // 2,560,000 (g0f / g1f / ua)
#define OFF_GB   2800000ULL    // 2,560,000 (g0b / g1b / wa)
#define OFF_H1   5360000ULL    // 1,280,000
#define OFF_OUT2 6640000ULL    // 1,280,000
#define OFF_SC   7920000ULL    // 158,400
#define OFF_NLL  8078400ULL    // 1,600
#define OFF_CNT  8080000ULL    // 1,600 ints (2 layers * 2 dir * 100 steps * 4)

// ---------------- embedding ----------------
__global__ __launch_bounds__(256) void embed_kernel(
    const int* __restrict__ tok, const int* __restrict__ pos,
    const float* __restrict__ wW, const float* __restrict__ pW,
    float* __restrict__ x0)
{
    int idx = blockIdx.x * 256 + threadIdx.x;
    if (idx >= BB * SS * DIN0) return;
    int n = idx / DIN0, d = idx % DIN0;
    x0[idx] = (d < 100) ? wW[tok[n] * 100 + d] : pW[pos[n] * 50 + (d - 100)];
}

// ---------------- generic NT GEMM: C[n][r] = bias[r] + sum_k A[n][k]*W[r][k] ----------------
// 64x64 tile, 256 threads, 4x4 micro-tile (contiguous), fp32.
__global__ __launch_bounds__(256) void gemm_nt_bias(
    const float* __restrict__ A, const float* __restrict__ W,
    const float* __restrict__ bias, float* __restrict__ C,
    int N, int K, int R)
{
    __shared__ __attribute__((aligned(16))) float As[16][68];
    __shared__ __attribute__((aligned(16))) float Ws[16][68];
    int tid = threadIdx.x;
    int tx = tid & 15, ty = tid >> 4;
    int row0 = blockIdx.y * 64, col0 = blockIdx.x * 64;
    float acc[4][4];
#pragma unroll
    for (int i = 0; i < 4; i++)
#pragma unroll
        for (int j = 0; j < 4; j++) acc[i][j] = 0.f;

    int ktiles = (K + 15) >> 4;
    for (int kt = 0; kt < ktiles; kt++) {
        int kb = kt << 4;
#pragma unroll
        for (int e = 0; e < 4; e++) {
            int i = tid + (e << 8);
            int r = i >> 4, kk = i & 15;
            int gk = kb + kk;
            As[kk][r] = (row0 + r < N && gk < K) ? A[(size_t)(row0 + r) * K + gk] : 0.f;
            Ws[kk][r] = (col0 + r < R && gk < K) ? W[(size_t)(col0 + r) * K + gk] : 0.f;
        }
        __syncthreads();
#pragma unroll
        for (int kk = 0; kk < 16; kk++) {
            float4 av = *(const float4*)&As[kk][ty * 4];
            float4 wv = *(const float4*)&Ws[kk][tx * 4];
            float a[4] = {av.x, av.y, av.z, av.w};
            float w[4] = {wv.x, wv.y, wv.z, wv.w};
#pragma unroll
            for (int i = 0; i < 4; i++)
#pragma unroll
                for (int j = 0; j < 4; j++) acc[i][j] = fmaf(a[i], w[j], acc[i][j]);
        }
        __syncthreads();
    }
#pragma unroll
    for (int i = 0; i < 4; i++) {
        int gr = row0 + ty * 4 + i;
        if (gr >= N) continue;
        int gc = col0 + tx * 4;
        if (gc >= R) continue;
        float4 o;
        o.x = acc[i][0] + (bias ? bias[gc + 0] : 0.f);
        o.y = acc[i][1] + (bias ? bias[gc + 1] : 0.f);
        o.z = acc[i][2] + (bias ? bias[gc + 2] : 0.f);
        o.w = acc[i][3] + (bias ? bias[gc + 3] : 0.f);
        *(float4*)&C[(size_t)gr * R + gc] = o;
    }
}

// ---------------- LSTM recurrence (one layer, both directions) ----------------
// 80 WGs per direction; WG owns 5 hidden units (20 gate rows). Weights LDS-resident.
// Per-step h exchange through global memory + device-scope counter barrier.
#define LSTM_KWG 80
#define LSTM_J   5
#define LSTM_ROWS 20
#define LSTM_THREADS 320
#define HSTRIDE 404

__global__ __launch_bounds__(LSTM_THREADS, 1) void lstm_layer_kernel(
    const float* __restrict__ Gf, const float* __restrict__ Gb,
    const float* __restrict__ Wf, const float* __restrict__ Wb,
    float* __restrict__ hbuf,   // [B][S][800]
    int* __restrict__ cnt)      // [2][100][4]
{
    int dir = blockIdx.x / LSTM_KWG;
    int wg  = blockIdx.x % LSTM_KWG;
    int j0  = wg * LSTM_J;
    const float* G = dir ? Gb : Gf;
    const float* W = dir ? Wb : Wf;
    int tid = threadIdx.x;

    __shared__ __attribute__((aligned(16))) float w_lds[LSTM_ROWS * 400];
    __shared__ __attribute__((aligned(16))) float h_lds[16 * HSTRIDE];
    __shared__ float gates_lds[LSTM_ROWS * 16];
    __shared__ float c_lds[LSTM_J * 16];

    for (int idx = tid; idx < LSTM_ROWS * 400; idx += LSTM_THREADS) {
        int lr = idx / 400, k = idx % 400;
        int g = lr / LSTM_J, jj = lr % LSTM_J;
        w_lds[idx] = W[(size_t)(g * 400 + j0 + jj) * 400 + k];
    }
    if (tid < LSTM_J * 16) c_lds[tid] = 0.f;
    __syncthreads();

    int b_l = tid & 15;
    int lr_l = tid >> 4;                 // 0..19
    int g_l = lr_l / LSTM_J, jj_l = lr_l % LSTM_J;
    int grow = g_l * 400 + j0 + jj_l;

    for (int t = 0; t < SS; t++) {
        int time = dir ? (SS - 1 - t) : t;
        // prefetch input-gate contribution (independent of recurrence)
        float gpre = G[(size_t)(b_l * SS + time) * G4 + grow];

        if (t > 0) {
            if (tid == 0) {
                int* c4 = cnt + (dir * SS + (t - 1)) * 4;
                for (int guard = 0; guard < (1 << 22); guard++) {
                    int s = 0;
#pragma unroll
                    for (int q = 0; q < 4; q++)
                        s += __hip_atomic_load(c4 + q, __ATOMIC_RELAXED, __HIP_MEMORY_SCOPE_AGENT);
                    if (s >= LSTM_KWG) break;
                    __builtin_amdgcn_s_sleep(2);
                }
                (void)__hip_atomic_load(c4, __ATOMIC_ACQUIRE, __HIP_MEMORY_SCOPE_AGENT);
            }
            __syncthreads();
            int tprev = dir ? (time + 1) : (time - 1);
            for (int idx = tid; idx < 16 * 400; idx += LSTM_THREADS) {
                int b = idx / 400, k = idx % 400;
                h_lds[b * HSTRIDE + k] = hbuf[(size_t)(b * SS + tprev) * H2 + dir * HH + k];
            }
        } else {
            for (int idx = tid; idx < 16 * HSTRIDE; idx += LSTM_THREADS) h_lds[idx] = 0.f;
        }
        __syncthreads();

        // recurrent dot: one (row, batch) per lane
        float acc = gpre;
        const float* wrow = &w_lds[lr_l * 400];
        const float* hrow = &h_lds[b_l * HSTRIDE];
#pragma unroll 4
        for (int k = 0; k < 400; k += 4) {
            float4 wv = *(const float4*)(wrow + k);
            float4 hv = *(const float4*)(hrow + k);
            acc = fmaf(wv.x, hv.x, acc);
            acc = fmaf(wv.y, hv.y, acc);
            acc = fmaf(wv.z, hv.z, acc);
            acc = fmaf(wv.w, hv.w, acc);
        }
        gates_lds[lr_l * 16 + b_l] = acc;
        __syncthreads();

        if (tid < LSTM_J * 16) {
            int jj = tid >> 4, b = tid & 15;
            float gi = gates_lds[(0 * LSTM_J + jj) * 16 + b];
            float gf = gates_lds[(1 * LSTM_J + jj) * 16 + b];
            float gg = gates_lds[(2 * LSTM_J + jj) * 16 + b];
            float go = gates_lds[(3 * LSTM_J + jj) * 16 + b];
            float si = 1.f / (1.f + expf(-gi));
            float sf = 1.f / (1.f + expf(-gf));
            float tg = tanhf(gg);
            float so = 1.f / (1.f + expf(-go));
            float c = sf * c_lds[tid] + si * tg;
            c_lds[tid] = c;
            float h = so * tanhf(c);
            hbuf[(size_t)(b * SS + time) * H2 + dir * HH + j0 + jj] = h;
        }
        __syncthreads();
        if (tid == 0) {
            __hip_atomic_fetch_add(cnt + (dir * SS + t) * 4 + (wg & 3), 1,
                                   __ATOMIC_RELEASE, __HIP_MEMORY_SCOPE_AGENT);
        }
    }
}

// ---------------- attention scores: g[b,i,j] = sum_h tanh(ua[b,j,h]+wa[b,i+1,h])*va[h] ----------------
#define ITILE 11
__global__ __launch_bounds__(256) void attn_scores_kernel(
    const float* __restrict__ ua, const float* __restrict__ wa,
    const float* __restrict__ va, float* __restrict__ scores)
{
    int b  = blockIdx.x / 9;
    int i0 = (blockIdx.x % 9) * ITILE;
    int tid = threadIdx.x;
    __shared__ float ua_t[100][101];
    __shared__ float wa_t[ITILE][102];
    __shared__ float sacc[ITILE][101];
    __shared__ float va_t[100];

    for (int p = tid; p < ITILE * 101; p += 256) ((float*)sacc)[p] = 0.f;

    for (int ht = 0; ht < 8; ht++) {
        int h0 = ht * 100;
        __syncthreads();   // protect tiles from previous iteration's readers
        for (int p = tid; p < 100 * 100; p += 256) {
            int j = p / 100, hh = p % 100;
            ua_t[j][hh] = ua[(size_t)(b * SS + j) * H2 + h0 + hh];
        }
        for (int p = tid; p < ITILE * 100; p += 256) {
            int il = p / 100, hh = p % 100;
            wa_t[il][hh] = wa[(size_t)(b * SS + i0 + il + 1) * H2 + h0 + hh];
        }
        if (tid < 100) va_t[tid] = va[h0 + tid];
        __syncthreads();
        for (int p = tid; p < ITILE * 100; p += 256) {
            int il = p / 100, j = p % 100;
            float acc = 0.f;
#pragma unroll 4
            for (int hh = 0; hh < 100; hh++) {
                float x = ua_t[j][hh] + wa_t[il][hh];
                float z = __expf(2.f * x);
                float th = 1.f - 2.f * __builtin_amdgcn_rcpf(z + 1.f);
                acc = fmaf(th, va_t[hh], acc);
            }
            sacc[il][j] += acc;
        }
    }
    __syncthreads();
    for (int p = tid; p < ITILE * 100; p += 256) {
        int il = p / 100, j = p % 100;
        scores[(size_t)(b * 99 + i0 + il) * 100 + j] = sacc[il][j];
    }
}

// ---------------- softmax / table / preds / nll per (b,i) row ----------------
__global__ __launch_bounds__(128) void attn_softmax_kernel(
    const float* __restrict__ scores, const float* __restrict__ out2,
    const int* __restrict__ head, float* __restrict__ outb,
    float* __restrict__ nll)
{
    int bi = blockIdx.x;           // b*99 + i
    int b = bi / 99, i = bi % 99;
    int j = threadIdx.x;
    __shared__ float sv[128];
    __shared__ int   si[128];
    __shared__ float red[128];

    float h_t = out2[(size_t)(b * SS + i + 1) * H2];
    float sj = -1e30f;
    if (j < 100) {
        sj = scores[(size_t)bi * 100 + j];
        float h_j = out2[(size_t)(b * SS + j) * H2];
        if (h_j == h_t) sj = -10000.0f;
    }
    sv[j] = sj; si[j] = j;
    __syncthreads();
    for (int off = 64; off >= 1; off >>= 1) {
        if (j < off) {
            float o = sv[j + off]; int oi = si[j + off];
            if (o > sv[j] || (o == sv[j] && oi < si[j])) { sv[j] = o; si[j] = oi; }
        }
        __syncthreads();
    }
    float m = sv[0]; int amax = si[0];
    __syncthreads();
    float e = (j < 100) ? __expf(sj - m) : 0.f;
    red[j] = e;
    __syncthreads();
    for (int off = 64; off >= 1; off >>= 1) {
        if (j < off) red[j] += red[j + off];
        __syncthreads();
    }
    float sum = red[0];
    float inv = 1.f / sum;
    if (j < 100) outb[1 + 1584 + (size_t)bi * 100 + j] = e * inv;
    if (j == 0) {
        outb[1 + bi] = (float)amax;
        int gold = head[b * SS + i + 1];
        bool valid = (gold != -1);
        int gc = gold < 0 ? 0 : (gold > 99 ? 99 : gold);
        float sgc = scores[(size_t)bi * 100 + gc];
        float hgc = out2[(size_t)(b * SS + gc) * H2];
        if (hgc == h_t) sgc = -10000.0f;
        nll[bi] = valid ? -(sgc - m - logf(sum)) : 0.f;
    }
}

// ---------------- final loss reduction ----------------
__global__ __launch_bounds__(128) void loss_kernel(
    const float* __restrict__ nll, const int* __restrict__ head,
    float* __restrict__ outb)
{
    __shared__ float red[128];
    int tid = threadIdx.x;
    float contrib = 0.f;
    if (tid < 99) {
        int i = tid;
        float tot = 0.f; int cv = 0;
        for (int b = 0; b < BB; b++) {
            tot += nll[b * 99 + i];
            cv += (head[b * SS + i + 1] != -1) ? 1 : 0;
        }
        int denom = cv > 0 ? cv : 1;
        contrib = tot / (float)denom;
    }
    red[tid] = contrib;
    __syncthreads();
    for (int off = 64; off >= 1; off >>= 1) {
        if (tid < off) red[tid] += red[tid + off];
        __syncthreads();
    }
    if (tid == 0) outb[0] = red[0];
}

// ---------------- launch ----------------
extern "C" void kernel_launch(void* const* d_in, const int* in_sizes, int n_in,
                              void* d_out, int out_size, void* d_ws, size_t ws_size,
                              hipStream_t stream) {
    const int*   tok     = (const int*)d_in[0];
    const int*   pos     = (const int*)d_in[1];
    const int*   head    = (const int*)d_in[2];
    const float* word_W  = (const float*)d_in[3];
    const float* pos_W   = (const float*)d_in[4];
    const float* l0f_Wih = (const float*)d_in[5];
    const float* l0f_Whh = (const float*)d_in[6];
    const float* l0f_b   = (const float*)d_in[7];
    const float* l0b_Wih = (const float*)d_in[8];
    const float* l0b_Whh = (const float*)d_in[9];
    const float* l0b_b   = (const float*)d_in[10];
    const float* l1f_Wih = (const float*)d_in[11];
    const float* l1f_Whh = (const float*)d_in[12];
    const float* l1f_b   = (const float*)d_in[13];
    const float* l1b_Wih = (const float*)d_in[14];
    const float* l1b_Whh = (const float*)d_in[15];
    const float* l1b_b   = (const float*)d_in[16];
    const float* ua_W    = (const float*)d_in[17];
    const float* ua_b    = (const float*)d_in[18];
    const float* wa_W    = (const float*)d_in[19];
    const float* wa_b    = (const float*)d_in[20];
    const float* va_W    = (const float*)d_in[21];

    float* ws   = (float*)d_ws;
    float* x0   = ws + OFF_X0;
    float* gf   = ws + OFF_GF;   // also g1f, then ua
    float* gb   = ws + OFF_GB;   // also g1b, then wa
    float* h1   = ws + OFF_H1;
    float* out2 = ws + OFF_OUT2;
    float* sc   = ws + OFF_SC;
    float* nllb = ws + OFF_NLL;
    int*   cnt  = (int*)(ws + OFF_CNT);
    float* outf = (float*)d_out;

    hipMemsetAsync(cnt, 0, 1600 * sizeof(int), stream);

    embed_kernel<<<dim3((BB * SS * DIN0 + 255) / 256), 256, 0, stream>>>(
        tok, pos, word_W, pos_W, x0);

    // layer-0 input projections
    gemm_nt_bias<<<dim3(25, 25), 256, 0, stream>>>(x0, l0f_Wih, l0f_b, gf, 1600, DIN0, G4);
    gemm_nt_bias<<<dim3(25, 25), 256, 0, stream>>>(x0, l0b_Wih, l0b_b, gb, 1600, DIN0, G4);
    // layer-0 recurrence
    lstm_layer_kernel<<<2 * LSTM_KWG, LSTM_THREADS, 0, stream>>>(
        gf, gb, l0f_Whh, l0b_Whh, h1, cnt);
    // layer-1 input projections
    gemm_nt_bias<<<dim3(25, 25), 256, 0, stream>>>(h1, l1f_Wih, l1f_b, gf, 1600, H2, G4);
    gemm_nt_bias<<<dim3(25, 25), 256, 0, stream>>>(h1, l1b_Wih, l1b_b, gb, 1600, H2, G4);
    // layer-1 recurrence
    lstm_layer_kernel<<<2 * LSTM_KWG, LSTM_THREADS, 0, stream>>>(
        gf, gb, l1f_Whh, l1b_Whh, out2, cnt + 800);
    // attention projections (reuse gf/gb slots)
    gemm_nt_bias<<<dim3(13, 25), 256, 0, stream>>>(out2, ua_W, ua_b, gf, 1600, H2, H2);
    gemm_nt_bias<<<dim3(13, 25), 256, 0, stream>>>(out2, wa_W, wa_b, gb, 1600, H2, H2);
    // scores, softmax/table/preds/nll, loss
    attn_scores_kernel<<<dim3(16 * 9), 256, 0, stream>>>(gf, gb, va_W, sc);
    attn_softmax_kernel<<<dim3(1584), 128, 0, stream>>>(sc, out2, head, outf, nllb);
    loss_kernel<<<dim3(1), 128, 0, stream>>>(nllb, head, outf);
}